// Round 1
// baseline (312.348 us; speedup 1.0000x reference)
//
#include <hip/hip_runtime.h>

#define HW 224
#define NIMG 64

// ---------------- union-find on a per-thread signed-char array -------------
// parent[c] >= 0 : index of parent cell
// parent[c] <  0 : root, value = -component_size  (size <= 121 fits in int8)

__device__ __forceinline__ int uf_find(signed char* p, int x) {
    int px;
    while ((px = p[x]) >= 0) {
        int g = p[px];
        if (g >= 0) { p[x] = (signed char)g; x = g; }   // path halving
        else x = px;
    }
    return x;
}

__device__ __forceinline__ void uf_union(signed char* p, int a, int b) {
    int ra = uf_find(p, a), rb = uf_find(p, b);
    if (ra == rb) return;
    int sa = -p[ra], sb = -p[rb];
    if (sa < sb) { int t = ra; ra = rb; rb = t; int ts = sa; sa = sb; sb = ts; }
    p[ra] = (signed char)(-(sa + sb));
    p[rb] = (signed char)ra;
}

// ---------------- stage 1: per-(image, channel, kernel) statistics ---------
// grid.x = 64 * 15;  block = 256
// interm layout: [b][metric(5)][kidx(5)][ch(3)]  (matches reference _rearrange)

__global__ __launch_bounds__(256) void fractal_stats(const float* __restrict__ in,
                                                     float* __restrict__ interm) {
    const int b    = blockIdx.x / 15;
    const int rem  = blockIdx.x % 15;
    const int ch   = rem / 5;
    const int kidx = rem % 5;
    const int k    = 3 + 2 * kidx;
    const int kk   = k * k;
    const int rows = (HW + k - 1) / k;      // == cols (square image)
    const int P    = rows * rows;
    const int pad  = (rows * k - HW) / 2;   // top == left pad (ph//2)

    __shared__ int hist[124];               // ones in [1, kk]; bin kk ignored later
    __shared__ int sums[3];                 // perc, ncomp, marea
    __shared__ signed char ufbuf[256 * 132];// 132-byte stride -> conflict-free-ish
    signed char* parent = &ufbuf[threadIdx.x * 132];

    for (int i = threadIdx.x; i < 124; i += 256) hist[i] = 0;
    if (threadIdx.x < 3) sums[threadIdx.x] = 0;
    __syncthreads();

    const float* img = in + (size_t)b * HW * HW * 3 + ch;
    const float fk = (float)k;

    int t_perc = 0, t_ncomp = 0, t_marea = 0;

    for (int p = threadIdx.x; p < P; p += 256) {
        const int pr = p / rows, pc = p % rows;
        const int y0 = pr * k - pad, x0 = pc * k - pad;
        // center pixel is always in-bounds for all k in {3,5,7,9,11}
        const float c = img[((y0 + (k >> 1)) * HW + (x0 + (k >> 1))) * 3];

        unsigned long long blo = 0ull, bhi = 0ull;
        int ones = 0;

        for (int i = 0; i < k; i++) {
            const int y = y0 + i;
            const bool yin = ((unsigned)y < (unsigned)HW);
            bool prev = false;
            for (int j = 0; j < k; j++) {
                const int x = x0 + j;
                float v = 0.0f;
                if (yin && (unsigned)x < (unsigned)HW) v = img[((size_t)y * HW + x) * 3];
                const bool bit = (fabsf(v - c) <= fk);
                const int cidx = i * k + j;
                if (bit) {
                    ones++;
                    if (cidx < 64) blo |= 1ull << cidx; else bhi |= 1ull << (cidx - 64);
                    parent[cidx] = (signed char)-1;
                    if (prev) uf_union(parent, cidx, cidx - 1);
                    if (i > 0) {
                        const int up = cidx - k;
                        const bool ub = (up < 64) ? ((blo >> up) & 1ull)
                                                  : ((bhi >> (up - 64)) & 1ull);
                        if (ub) uf_union(parent, cidx, up);
                    }
                }
                prev = bit;
            }
        }

        // component count + largest component size (roots have negative parent)
        int ncomp = 0, maxsz = 0;
        unsigned long long m = blo;
        while (m) {
            const int cix = __builtin_ctzll(m); m &= m - 1;
            const int pv = parent[cix];
            if (pv < 0) { ncomp++; if (-pv > maxsz) maxsz = -pv; }
        }
        m = bhi;
        while (m) {
            const int cix = 64 + __builtin_ctzll(m); m &= m - 1;
            const int pv = parent[cix];
            if (pv < 0) { ncomp++; if (-pv > maxsz) maxsz = -pv; }
        }
        const int bgcnt = kk - ones;                 // background label 0 count
        const int marea = (bgcnt > maxsz) ? bgcnt : maxsz;

        t_ncomp += ncomp;
        t_marea += marea;
        if ((float)ones / (float)kk >= 0.59275f) t_perc++;
        atomicAdd(&hist[ones], 1);
    }

    atomicAdd(&sums[0], t_perc);
    atomicAdd(&sums[1], t_ncomp);
    atomicAdd(&sums[2], t_marea);
    __syncthreads();

    if (threadIdx.x == 0) {
        const float Pf = (float)P;
        float fd = 0.0f, m1 = 0.0f, m2 = 0.0f;
        for (int s = 0; s < kk; s++) {              // bin kk (ones==k*k) excluded
            const float prob = (float)hist[s] / Pf;
            const float n = (float)(s + 1);
            fd += prob / n;
            m1 += prob * n;
            m2 += prob * prob * n;
        }
        const float lac = (m2 - m1 * m1) / (m1 * m1);
        float* o = interm + (size_t)b * 75 + kidx * 3 + ch;
        o[0]      = (float)(sums[1] / P);   // acn  (integer floor mean)
        o[15]     = (float)(sums[0] / P);   // acp
        o[30]     = (float)(sums[2] / P);   // acma
        o[45]     = lac;                    // lac
        o[60]     = fd;                     // fd
    }
}

// ---------------- stage 2: 5x5 -> 224x224 bilinear (jax half-pixel) --------

__global__ __launch_bounds__(256) void fractal_resize(const float* __restrict__ interm,
                                                      float* __restrict__ out, int total) {
    const int idx = blockIdx.x * 256 + threadIdx.x;
    if (idx >= total) return;
    const int ch = idx % 3;
    int t = idx / 3;
    const int x = t % HW; t /= HW;
    const int y = t % HW;
    const int b = t / HW;

    const float sc = 5.0f / 224.0f;
    const float uy = ((float)y + 0.5f) * sc - 0.5f;   // in (-0.5, 4.5)
    const float ux = ((float)x + 0.5f) * sc - 0.5f;

    const float fy = floorf(uy), fx = floorf(ux);
    const float wy = uy - fy,    wx = ux - fx;
    int y0 = (int)fy, x0 = (int)fx;
    int y1 = y0 + 1,  x1 = x0 + 1;
    if (y0 < 0) y0 = 0; if (x0 < 0) x0 = 0;
    if (y1 > 4) y1 = 4; if (x1 > 4) x1 = 4;

    const float* g = interm + (size_t)b * 75 + ch;
    const float v00 = g[(y0 * 5 + x0) * 3];
    const float v01 = g[(y0 * 5 + x1) * 3];
    const float v10 = g[(y1 * 5 + x0) * 3];
    const float v11 = g[(y1 * 5 + x1) * 3];

    out[idx] = (1.0f - wy) * ((1.0f - wx) * v00 + wx * v01)
             +         wy  * ((1.0f - wx) * v10 + wx * v11);
}

// ---------------- launcher -------------------------------------------------

extern "C" void kernel_launch(void* const* d_in, const int* in_sizes, int n_in,
                              void* d_out, int out_size, void* d_ws, size_t ws_size,
                              hipStream_t stream) {
    const float* in = (const float*)d_in[0];
    float* out = (float*)d_out;
    float* interm = (float*)d_ws;   // 64*5*5*3 floats = 19200 B

    fractal_stats<<<NIMG * 15, 256, 0, stream>>>(in, interm);
    fractal_resize<<<(out_size + 255) / 256, 256, 0, stream>>>(interm, out, out_size);
}

// Round 2
// 185.788 us; speedup vs baseline: 1.6812x; 1.6812x over previous
//
#include <hip/hip_runtime.h>

#define HW 224
#define NIMG 64
#define NPIX ((size_t)NIMG * HW * HW)

// ---------------- 128-bit bitmask helpers (registers only) -----------------
struct U128 { unsigned long long lo, hi; };
__device__ __forceinline__ U128 u_or  (U128 a, U128 b){ return {a.lo|b.lo, a.hi|b.hi}; }
__device__ __forceinline__ U128 u_and (U128 a, U128 b){ return {a.lo&b.lo, a.hi&b.hi}; }
__device__ __forceinline__ U128 u_andn(U128 a, U128 b){ return {a.lo&~b.lo, a.hi&~b.hi}; }
__device__ __forceinline__ bool u_eq(U128 a, U128 b){ return a.lo==b.lo && a.hi==b.hi; }
__device__ __forceinline__ bool u_nz(U128 a){ return (a.lo | a.hi) != 0ull; }
__device__ __forceinline__ U128 u_shl(U128 a, int n){           // 1 <= n < 64
    return { a.lo << n, (a.hi << n) | (a.lo >> (64 - n)) };
}
__device__ __forceinline__ U128 u_shr(U128 a, int n){
    return { (a.lo >> n) | (a.hi << (64 - n)), a.hi >> n };
}
__device__ __forceinline__ int u_pop(U128 a){ return __popcll(a.lo) + __popcll(a.hi); }
__device__ __forceinline__ U128 u_low(U128 a){
    if (a.lo) return { a.lo & (0ull - a.lo), 0ull };
    return { 0ull, a.hi & (0ull - a.hi) };
}

// ---------------- stage 1 body, K compile-time for full unroll -------------
// S = element stride (1 = planar plane, 3 = interleaved fallback)

template<int K, int S>
__device__ __forceinline__ void stats_body(const float* __restrict__ img,
                                           float* __restrict__ o,
                                           int hist[4][124], int* sums) {
    constexpr int KK   = K * K;
    constexpr int ROWS = (HW + K - 1) / K;
    constexpr int P    = ROWS * ROWS;
    constexpr int PAD  = (ROWS * K - HW) / 2;
    const int wid = threadIdx.x >> 6;

    // column-boundary masks (compile-time constants after unroll)
    U128 leftCol{0,0}, rightCol{0,0};
#pragma unroll
    for (int i = 0; i < K; i++) {
        const int cl = i * K, cr = i * K + K - 1;
        if (cl < 64) leftCol.lo  |= 1ull << cl; else leftCol.hi  |= 1ull << (cl - 64);
        if (cr < 64) rightCol.lo |= 1ull << cr; else rightCol.hi |= 1ull << (cr - 64);
    }

    int t_perc = 0, t_ncomp = 0, t_marea = 0;

    for (int p = threadIdx.x; p < P; p += 256) {
        const int pr = p / ROWS, pc = p - pr * ROWS;
        const int y0 = pr * K - PAD, x0 = pc * K - PAD;
        // center pixel always in-bounds for K in {3,5,7,9,11}
        const float cen = img[((size_t)(y0 + K / 2) * HW + (x0 + K / 2)) * S];

        // binarize: out-of-bounds pixels are zero-padded (v = 0)
        U128 msk{0, 0};
#pragma unroll
        for (int i = 0; i < K; i++) {
            const int y = y0 + i;
            const bool yin = (unsigned)y < (unsigned)HW;
#pragma unroll
            for (int j = 0; j < K; j++) {
                const int x = x0 + j;
                const bool inb = yin && ((unsigned)x < (unsigned)HW);
                const float v = inb ? img[((size_t)y * HW + x) * S] : 0.0f;
                const unsigned long long bit = (fabsf(v - cen) <= (float)K) ? 1ull : 0ull;
                const int c = i * K + j;
                if (c < 64) msk.lo |= bit << c; else msk.hi |= bit << (c - 64);
            }
        }
        const int ones = u_pop(msk);

        // connected components: bit-parallel flood fill, all in registers
        int ncomp = 0, maxsz = 0;
        U128 m = msk;
        while (u_nz(m)) {
            U128 s = u_low(m);
            for (;;) {
                U128 g = s;
                g = u_or(g, u_shl(u_andn(s, rightCol), 1));   // right neighbor
                g = u_or(g, u_shr(u_andn(s, leftCol), 1));    // left neighbor
                g = u_or(g, u_shl(s, K));                     // down
                g = u_or(g, u_shr(s, K));                     // up
                g = u_and(g, m);
                if (u_eq(g, s)) break;
                s = g;
            }
            ncomp++;
            const int sz = u_pop(s);
            if (sz > maxsz) maxsz = sz;
            m = u_andn(m, s);
        }

        const int bgcnt = KK - ones;                 // background label 0 count
        const int marea = (bgcnt > maxsz) ? bgcnt : maxsz;

        t_ncomp += ncomp;
        t_marea += marea;
        if ((float)ones / (float)KK >= 0.59275f) t_perc++;
        atomicAdd(&hist[wid][ones], 1);
    }

    atomicAdd(&sums[0], t_perc);
    atomicAdd(&sums[1], t_ncomp);
    atomicAdd(&sums[2], t_marea);
    __syncthreads();

    if (threadIdx.x == 0) {
        const float Pf = (float)P;
        float fd = 0.0f, m1 = 0.0f, m2 = 0.0f;
        for (int s = 0; s < KK; s++) {               // bin KK (ones==K*K) excluded
            const float prob = (float)(hist[0][s] + hist[1][s] + hist[2][s] + hist[3][s]) / Pf;
            const float n = (float)(s + 1);
            fd += prob / n;
            m1 += prob * n;
            m2 += prob * prob * n;
        }
        const float lac = (m2 - m1 * m1) / (m1 * m1);
        o[0]  = (float)(sums[1] / P);   // acn  (integer floor mean)
        o[15] = (float)(sums[0] / P);   // acp
        o[30] = (float)(sums[2] / P);   // acma
        o[45] = lac;
        o[60] = fd;
    }
}

// grid.x = 64 * 15 ; block = 256
// interm layout: [b][metric(5)][kidx(5)][ch(3)]  (matches reference _rearrange)
template<int S>
__global__ __launch_bounds__(256) void fractal_stats(const float* __restrict__ in,
                                                     float* __restrict__ interm) {
    const int b    = blockIdx.x / 15;
    const int rem  = blockIdx.x % 15;
    const int ch   = rem / 5;
    const int kidx = rem % 5;

    __shared__ int hist[4][124];                     // per-wave copies
    __shared__ int sums[3];                          // perc, ncomp, marea
    for (int i = threadIdx.x; i < 4 * 124; i += 256) ((int*)hist)[i] = 0;
    if (threadIdx.x < 3) sums[threadIdx.x] = 0;
    __syncthreads();

    const float* img = (S == 1) ? in + ((size_t)ch * NIMG + b) * HW * HW
                                : in + (size_t)b * HW * HW * 3 + ch;
    float* o = interm + (size_t)b * 75 + kidx * 3 + ch;

    switch (kidx) {                                  // block-uniform branch
        case 0: stats_body<3,  S>(img, o, hist, sums); break;
        case 1: stats_body<5,  S>(img, o, hist, sums); break;
        case 2: stats_body<7,  S>(img, o, hist, sums); break;
        case 3: stats_body<9,  S>(img, o, hist, sums); break;
        case 4: stats_body<11, S>(img, o, hist, sums); break;
    }
}

// ---------------- NHWC -> planar (per-channel) ------------------------------
__global__ __launch_bounds__(256) void deinterleave(const float* __restrict__ in,
                                                    float* __restrict__ planes) {
    const size_t pix = (size_t)blockIdx.x * 256 + threadIdx.x;
    if (pix >= NPIX) return;
    const float v0 = in[pix * 3 + 0];
    const float v1 = in[pix * 3 + 1];
    const float v2 = in[pix * 3 + 2];
    planes[pix]            = v0;
    planes[NPIX + pix]     = v1;
    planes[2 * NPIX + pix] = v2;
}

// ---------------- stage 2: 5x5 -> 224x224 bilinear (jax half-pixel) --------
__global__ __launch_bounds__(256) void fractal_resize(const float* __restrict__ interm,
                                                      float* __restrict__ out, int total) {
    const int idx = blockIdx.x * 256 + threadIdx.x;
    if (idx >= total) return;
    const int ch = idx % 3;
    int t = idx / 3;
    const int x = t % HW; t /= HW;
    const int y = t % HW;
    const int b = t / HW;

    const float sc = 5.0f / 224.0f;
    const float uy = ((float)y + 0.5f) * sc - 0.5f;   // in (-0.5, 4.5)
    const float ux = ((float)x + 0.5f) * sc - 0.5f;

    const float fy = floorf(uy), fx = floorf(ux);
    const float wy = uy - fy,    wx = ux - fx;
    int y0 = (int)fy, x0 = (int)fx;
    int y1 = y0 + 1,  x1 = x0 + 1;
    if (y0 < 0) y0 = 0; if (x0 < 0) x0 = 0;
    if (y1 > 4) y1 = 4; if (x1 > 4) x1 = 4;

    const float* g = interm + (size_t)b * 75 + ch;
    const float v00 = g[(y0 * 5 + x0) * 3];
    const float v01 = g[(y0 * 5 + x1) * 3];
    const float v10 = g[(y1 * 5 + x0) * 3];
    const float v11 = g[(y1 * 5 + x1) * 3];

    out[idx] = (1.0f - wy) * ((1.0f - wx) * v00 + wx * v01)
             +         wy  * ((1.0f - wx) * v10 + wx * v11);
}

// ---------------- launcher -------------------------------------------------
extern "C" void kernel_launch(void* const* d_in, const int* in_sizes, int n_in,
                              void* d_out, int out_size, void* d_ws, size_t ws_size,
                              hipStream_t stream) {
    const float* in = (const float*)d_in[0];
    float* out = (float*)d_out;
    float* interm = (float*)d_ws;                    // 64*5*5*3 floats = 19200 B

    const size_t planes_off = 19456;                 // 256B-aligned
    const size_t need = planes_off + 3 * NPIX * sizeof(float);

    if (ws_size >= need) {
        float* planes = (float*)((char*)d_ws + planes_off);
        deinterleave<<<(int)((NPIX + 255) / 256), 256, 0, stream>>>(in, planes);
        fractal_stats<1><<<NIMG * 15, 256, 0, stream>>>(planes, interm);
    } else {
        fractal_stats<3><<<NIMG * 15, 256, 0, stream>>>(in, interm);
    }
    fractal_resize<<<(out_size + 255) / 256, 256, 0, stream>>>(interm, out, out_size);
}